// Round 15
// baseline (273.593 us; speedup 1.0000x reference)
//
#include <hip/hip_runtime.h>

// ---------------------------------------------------------------------------
// LIIF forward, MI355X.  ALL tensors are float32 (per reference source).
// R15 = R14 with ONE change: gmat_kernel gets depth-3 A/B/C prefetch with
// FULL tiles (2m x 4n = 8 MFMA/step burst kept — R10/R13 lesson: shrinking
// the burst cancels the gain) + __launch_bounds__(256,1) (1 WG/CU anyway at
// 144 WGs; 512-reg budget absorbs the 72 extra fragment VGPRs, no spill).
// Gap accounting: R3-R11 gap (prep+conv+overhead) = 96-100 us stable;
// R12/R14 gap = 147 us  =>  gmat ~ 50 us: 1 wave/SIMD, 36 K-steps each
// paying ~600 cyc load latency with only depth-1 cover.  Depth-3 covers
// ~768 cyc -> predicted gmat ~15 us.
// R12 recap: G[pixel] = W0[0:576]^T unfold(pixel) in MFMA C-layout order
// (ch' = mt*32+hi*16+q*4+i <-> m = 8q+4hi+i); liif L0 = G gather (acc init)
// + one K=16 ext MFMA step; layers 1-3 32x32x16 ping-pong, packed cvt
// writeback, post-barrier weight loads.  liif = 121 us @ MfmaUtil 35%.
// Tripwires: liif counters must be unchanged (byte-identical); absmax >
// 5.86e-3 => bug; total within 10 us of 268 => gap is harness-fixed floor.
// ---------------------------------------------------------------------------

typedef _Float16 half8   __attribute__((ext_vector_type(8)));
typedef _Float16 half4v  __attribute__((ext_vector_type(4)));
typedef _Float16 half2v  __attribute__((ext_vector_type(2)));
typedef float    float4v __attribute__((ext_vector_type(4)));
typedef float    floatx16 __attribute__((ext_vector_type(16)));

// clamped f32->f16 (prep/conv side only)
__device__ __forceinline__ _Float16 to_h(float v) {
  return (_Float16)fminf(fmaxf(v, -60000.0f), 60000.0f);
}

#define NQ 30000
#define QT 469   // ceil(NQ/64) real tiles per batch
#define QTP 472  // padded to 4-multiple for XCD-partitioned grid (944 blocks)

// ---------------- weight repack (coalesced, R14) ---------------------------
// wp layout: [kb][n][8] f16, element (n, k=kb*8+i) at ((kb*N + n)*8 + i).
__global__ void prep_kernel(const float* __restrict__ w0,
                            const float* __restrict__ w1,
                            const float* __restrict__ w2,
                            const float* __restrict__ w3,
                            const float* __restrict__ w4,
                            _Float16* __restrict__ p0, _Float16* __restrict__ p1,
                            _Float16* __restrict__ p2, _Float16* __restrict__ p3,
                            _Float16* __restrict__ p4) {
  int idx = blockIdx.x * 256 + threadIdx.x;
  if (idx < 18944) {                       // wp0: (kb,n), kb 0..73
    int kb = idx >> 8, n = idx & 255;
    half8 hv;
#pragma unroll
    for (int i = 0; i < 8; ++i) {
      int f = kb * 8 + i;                  // permuted feature index
      float v = 0.0f;
      if (f < 576)      v = w0[((f & 63) * 9 + (f >> 6)) * 256 + n];
      else if (f < 580) v = w0[f * 256 + n];
      hv[i] = (_Float16)v;
    }
    *(half8*)(p0 + idx * 8) = hv;
  } else if (idx < 43520) {                // wp1..3: l*(32kb*256n)
    int j = idx - 18944;
    int l = j >> 13;                       // 8192 = 32*256 per layer
    int j2 = j & 8191;
    int kb = j2 >> 8, n = j2 & 255;
    const float* w = (l == 0) ? w1 : (l == 1) ? w2 : w3;
    _Float16* p = (l == 0) ? p1 : (l == 1) ? p2 : p3;
    half8 hv;
#pragma unroll
    for (int i = 0; i < 8; ++i)
      hv[i] = (_Float16)w[(kb * 8 + i) * 256 + n];
    *(half8*)(p + j2 * 8) = hv;
  } else if (idx < 44032) {                // wp4: 32kb * 16n
    int j = idx - 43520;
    int kb = j >> 4, n = j & 15;
    half8 hv;
#pragma unroll
    for (int i = 0; i < 8; ++i) {
      float v = (n < 3) ? w4[(kb * 8 + i) * 3 + n] : 0.0f;
      hv[i] = (_Float16)v;
    }
    *(half8*)(p4 + j * 8) = hv;
  }
}

// ---------------- conv 3x3 (3->64) + bias + tanh, zero-padded borders ------
__global__ void conv_kernel(const float* __restrict__ inp,
                            const float* __restrict__ cw,
                            const float* __restrict__ cb,
                            _Float16* __restrict__ P) {
  __shared__ __align__(16) float s_w[1728];
  __shared__ __align__(16) float s_b[64];
  for (int i = threadIdx.x; i < 1728; i += 256) s_w[i] = cw[i];
  if (threadIdx.x < 64) s_b[threadIdx.x] = cb[threadIdx.x];
  __syncthreads();
  int tid = blockIdx.x * 256 + threadIdx.x;
  if (tid >= 2 * 98 * 98) return;
  int b = tid / 9604;
  int rem = tid % 9604;
  int yy = rem / 98, xx = rem % 98;
  alignas(16) _Float16 outv[64];
  if (yy == 0 || yy == 97 || xx == 0 || xx == 97) {
#pragma unroll
    for (int c = 0; c < 64; ++c) outv[c] = (_Float16)0.0f;
  } else {
    int y = yy - 1, x = xx - 1;
    float win[27];
#pragma unroll
    for (int ci = 0; ci < 3; ++ci)
#pragma unroll
      for (int ky = 0; ky < 3; ++ky)
#pragma unroll
        for (int kx = 0; kx < 3; ++kx) {
          int yi = y + ky - 1, xi = x + kx - 1;
          float v = 0.0f;
          if (yi >= 0 && yi < 96 && xi >= 0 && xi < 96)
            v = inp[((b * 3 + ci) * 96 + yi) * 96 + xi];
          win[ci * 9 + ky * 3 + kx] = v;
        }
    for (int co = 0; co < 64; ++co) {
      float acc = s_b[co];
#pragma unroll
      for (int k = 0; k < 27; ++k) acc = fmaf(win[k], s_w[co * 27 + k], acc);
      outv[co] = (_Float16)tanhf(acc);
    }
  }
  _Float16* dst = P + tid * 64;
#pragma unroll
  for (int j = 0; j < 8; ++j) ((half8*)dst)[j] = ((const half8*)outv)[j];
}

// ---------------- G precompute: G[pixel] = W0[0:576]^T * unfold(pixel) -----
// 144 WGs x 128 pixels, full tiles (2m x 4n, 8 MFMA/step), depth-3 A/B/C
// prefetch (36 = 12x3 exact), constant indices, launch_bounds(256,1).
// Store pre-permuted: value m = 8q+4hi+i of tile mt at
// G[pix*256 + mt*32 + hi*16 + q*4 + i]  (mt = 2*wv + mt2).
__global__ __launch_bounds__(256, 1) void gmat_kernel(
    const _Float16* __restrict__ P,
    const _Float16* __restrict__ wp0,
    _Float16* __restrict__ G) {
  const int t    = threadIdx.x;
  const int lane = t & 63;
  const int wv   = t >> 6;
  const int ln32 = lane & 31;
  const int hi   = lane >> 5;
  const int pb   = blockIdx.x * 128;

  int voffB[4]; int gidx[4];
#pragma unroll
  for (int nt2 = 0; nt2 < 4; ++nt2) {
    int g   = pb + nt2 * 32 + ln32;      // 0..18431
    int bb  = g / 9216;
    int rem = g - bb * 9216;
    int ry  = rem / 96;
    int rx  = rem - ry * 96;
    int pix = (bb * 98 + ry) * 98 + rx;  // padded-grid window base
    voffB[nt2] = pix * 128 + hi * 16;
    gidx[nt2]  = pix * 256;
  }
  const char* Pb = (const char*)P;
  const _Float16* wb0 = wp0 + (hi * 256 + wv * 64 + ln32) * 8;

  floatx16 acc[2][4];
#pragma unroll
  for (int mt2 = 0; mt2 < 2; ++mt2)
#pragma unroll
    for (int nt2 = 0; nt2 < 4; ++nt2) acc[mt2][nt2] = (floatx16)(0.0f);

  half8 bfA[4], bfB[4], bfC[4], afA[2], afB[2], afC[2];
  // preload steps 0,1,2 (patch 0, chunks 0/1/2)
#pragma unroll
  for (int nt2 = 0; nt2 < 4; ++nt2) {
    bfA[nt2] = *(const half8*)(Pb + voffB[nt2]);
    bfB[nt2] = *(const half8*)(Pb + voffB[nt2] + 32);
    bfC[nt2] = *(const half8*)(Pb + voffB[nt2] + 64);
  }
  afA[0] = *(const half8*)(wb0);          afA[1] = *(const half8*)(wb0 + 256);
  afB[0] = *(const half8*)(wb0 + 4096);   afB[1] = *(const half8*)(wb0 + 4096 + 256);
  afC[0] = *(const half8*)(wb0 + 8192);   afC[1] = *(const half8*)(wb0 + 8192 + 256);

#pragma unroll 1
  for (int s = 0; s < 36; s += 3) {
    // phase A: consume step s, prefetch s+3
#pragma unroll
    for (int mt2 = 0; mt2 < 2; ++mt2)
#pragma unroll
      for (int nt2 = 0; nt2 < 4; ++nt2)
        acc[mt2][nt2] = __builtin_amdgcn_mfma_f32_32x32x16_f16(
            afA[mt2], bfA[nt2], acc[mt2][nt2], 0, 0, 0);
    {
      const int sp = (s + 3 <= 35) ? (s + 3) : 35;
      const int patch = sp >> 2;
      const int off = ((patch / 3) * 98 + (patch % 3)) * 128 + ((sp & 3) << 5);
      afA[0] = *(const half8*)(wb0 + sp * 4096);
      afA[1] = *(const half8*)(wb0 + sp * 4096 + 256);
#pragma unroll
      for (int nt2 = 0; nt2 < 4; ++nt2)
        bfA[nt2] = *(const half8*)(Pb + voffB[nt2] + off);
    }
    // phase B: consume step s+1, prefetch s+4
#pragma unroll
    for (int mt2 = 0; mt2 < 2; ++mt2)
#pragma unroll
      for (int nt2 = 0; nt2 < 4; ++nt2)
        acc[mt2][nt2] = __builtin_amdgcn_mfma_f32_32x32x16_f16(
            afB[mt2], bfB[nt2], acc[mt2][nt2], 0, 0, 0);
    {
      const int sp = (s + 4 <= 35) ? (s + 4) : 35;
      const int patch = sp >> 2;
      const int off = ((patch / 3) * 98 + (patch % 3)) * 128 + ((sp & 3) << 5);
      afB[0] = *(const half8*)(wb0 + sp * 4096);
      afB[1] = *(const half8*)(wb0 + sp * 4096 + 256);
#pragma unroll
      for (int nt2 = 0; nt2 < 4; ++nt2)
        bfB[nt2] = *(const half8*)(Pb + voffB[nt2] + off);
    }
    // phase C: consume step s+2, prefetch s+5
#pragma unroll
    for (int mt2 = 0; mt2 < 2; ++mt2)
#pragma unroll
      for (int nt2 = 0; nt2 < 4; ++nt2)
        acc[mt2][nt2] = __builtin_amdgcn_mfma_f32_32x32x16_f16(
            afC[mt2], bfC[nt2], acc[mt2][nt2], 0, 0, 0);
    {
      const int sp = (s + 5 <= 35) ? (s + 5) : 35;
      const int patch = sp >> 2;
      const int off = ((patch / 3) * 98 + (patch % 3)) * 128 + ((sp & 3) << 5);
      afC[0] = *(const half8*)(wb0 + sp * 4096);
      afC[1] = *(const half8*)(wb0 + sp * 4096 + 256);
#pragma unroll
      for (int nt2 = 0; nt2 < 4; ++nt2)
        bfC[nt2] = *(const half8*)(Pb + voffB[nt2] + off);
    }
  }
  // permuted store (RNE cvt): regs 0..15 already in ch' order q*4+i
#pragma unroll
  for (int mt2 = 0; mt2 < 2; ++mt2)
#pragma unroll
    for (int nt2 = 0; nt2 < 4; ++nt2) {
      half8 c0, c1;
#pragma unroll
      for (int j = 0; j < 8; ++j) {
        c0[j] = (_Float16)acc[mt2][nt2][j];
        c1[j] = (_Float16)acc[mt2][nt2][8 + j];
      }
      _Float16* ga = G + gidx[nt2] + (wv * 2 + mt2) * 32 + hi * 16;
      *(half8*)(ga)     = c0;
      *(half8*)(ga + 8) = c1;
    }
}

// ---------------- main: gather + MLP + blend -------------------------------
// WG = 256 thr = 4 waves = 64 queries x 2 offsets (128 rows) per pass.
// 32x32x16 C/D (measured m74/m101): n=lane&31, m=(reg&3)+8*(reg>>2)+4*(lane>>5).
__device__ __forceinline__ void writeback32(floatx16 (&acc)[2][4],
                                            const float* __restrict__ sb,
                                            _Float16 (*s_h)[264],
                                            int wv, int ln32, int hi) {
#pragma unroll
  for (int mt2 = 0; mt2 < 2; ++mt2) {
    const int mb = wv * 64 + mt2 * 32 + 4 * hi;
#pragma unroll
    for (int g = 0; g < 4; ++g) {
      const int m0 = mb + 8 * g;
      float b0 = sb[m0], b1 = sb[m0 + 1], b2 = sb[m0 + 2], b3 = sb[m0 + 3];
#pragma unroll
      for (int nt2 = 0; nt2 < 4; ++nt2) {
        const int n = nt2 * 32 + ln32;
        float v0 = fmaxf(acc[mt2][nt2][4 * g + 0] + b0, 0.0f);
        float v1 = fmaxf(acc[mt2][nt2][4 * g + 1] + b1, 0.0f);
        float v2 = fmaxf(acc[mt2][nt2][4 * g + 2] + b2, 0.0f);
        float v3 = fmaxf(acc[mt2][nt2][4 * g + 3] + b3, 0.0f);
        half2v lo  = __builtin_bit_cast(half2v, __builtin_amdgcn_cvt_pkrtz(v0, v1));
        half2v hi2 = __builtin_bit_cast(half2v, __builtin_amdgcn_cvt_pkrtz(v2, v3));
        half4v hv;
        hv[0] = lo[0]; hv[1] = lo[1]; hv[2] = hi2[0]; hv[3] = hi2[1];
        *(half4v*)(&s_h[n][m0]) = hv;
      }
    }
  }
}

// K=256 layer from s_h, ping-pong pipelined; loads after caller's barrier.
__device__ __forceinline__ void layer256(const _Float16* __restrict__ wbl,
                                         _Float16 (*s_h)[264],
                                         int ln32, int hi,
                                         floatx16 (&acc)[2][4]) {
#pragma unroll
  for (int mt2 = 0; mt2 < 2; ++mt2)
#pragma unroll
    for (int nt2 = 0; nt2 < 4; ++nt2) acc[mt2][nt2] = (floatx16)(0.0f);
  half8 afA[2], afB[2], bfA[4], bfB[4];
  afA[0] = *(const half8*)(wbl);
  afA[1] = *(const half8*)(wbl + 256);
  afB[0] = *(const half8*)(wbl + 4096);
  afB[1] = *(const half8*)(wbl + 4096 + 256);
#pragma unroll
  for (int nt2 = 0; nt2 < 4; ++nt2) {
    bfA[nt2] = *(const half8*)(&s_h[nt2 * 32 + ln32][hi * 8]);
    bfB[nt2] = *(const half8*)(&s_h[nt2 * 32 + ln32][16 + hi * 8]);
  }
#pragma unroll 1
  for (int s = 0; s < 16; s += 2) {
#pragma unroll
    for (int mt2 = 0; mt2 < 2; ++mt2)
#pragma unroll
      for (int nt2 = 0; nt2 < 4; ++nt2)
        acc[mt2][nt2] = __builtin_amdgcn_mfma_f32_32x32x16_f16(
            afA[mt2], bfA[nt2], acc[mt2][nt2], 0, 0, 0);
    {
      const int sc = (s + 2 < 16) ? (s + 2) : 0;
      const int sw = (s + 2 < 16) ? (s + 2) : 15;
      afA[0] = *(const half8*)(wbl + sw * 4096);
      afA[1] = *(const half8*)(wbl + sw * 4096 + 256);
#pragma unroll
      for (int nt2 = 0; nt2 < 4; ++nt2)
        bfA[nt2] = *(const half8*)(&s_h[nt2 * 32 + ln32][sc * 16 + hi * 8]);
    }
#pragma unroll
    for (int mt2 = 0; mt2 < 2; ++mt2)
#pragma unroll
      for (int nt2 = 0; nt2 < 4; ++nt2)
        acc[mt2][nt2] = __builtin_amdgcn_mfma_f32_32x32x16_f16(
            afB[mt2], bfB[nt2], acc[mt2][nt2], 0, 0, 0);
    {
      const int sc = (s + 3 < 16) ? (s + 3) : 0;
      const int sw = (s + 3 < 16) ? (s + 3) : 15;
      afB[0] = *(const half8*)(wbl + sw * 4096);
      afB[1] = *(const half8*)(wbl + sw * 4096 + 256);
#pragma unroll
      for (int nt2 = 0; nt2 < 4; ++nt2)
        bfB[nt2] = *(const half8*)(&s_h[nt2 * 32 + ln32][sc * 16 + hi * 8]);
    }
  }
}

__global__ __launch_bounds__(256, 2) void liif_main(
    const float* __restrict__ coord, const float* __restrict__ cell,
    const float* __restrict__ bias0, const float* __restrict__ bias1,
    const float* __restrict__ bias2, const float* __restrict__ bias3,
    const float* __restrict__ bias4,
    const _Float16* __restrict__ G,
    const _Float16* __restrict__ wp0, const _Float16* __restrict__ wp1,
    const _Float16* __restrict__ wp2, const _Float16* __restrict__ wp3,
    const _Float16* __restrict__ wp4,
    float* __restrict__ out) {
  __shared__ __align__(16) int      s_pix[4][64];
  __shared__ __align__(16) float    s_area[4][64];
  __shared__ __align__(16) _Float16 s_ext[4][64][8];
  __shared__ __align__(16) float    s_bias[1028];
  __shared__ __align__(16) float    s_out[128][4];
  __shared__ __align__(16) float    s_num[64][4];
  __shared__ __align__(16) _Float16 s_h[128][264]; // stride 132 dw = 4 mod 32

  const int t   = threadIdx.x;
  const int blk = blockIdx.x;
  const int bb  = (blk & 4) >> 2;            // batch = bit2 -> stable per XCD
  const int tile = (blk >> 3) * 4 + (blk & 3);
  const int q0  = tile * 64;

  // ---- stage biases into LDS (1027 f32) ----
  for (int i = t; i < 1027; i += 256) {
    float v;
    if (i < 256)       v = bias0[i];
    else if (i < 512)  v = bias1[i - 256];
    else if (i < 768)  v = bias2[i - 512];
    else if (i < 1024) v = bias3[i - 768];
    else               v = bias4[i - 1024];
    s_bias[i] = v;
  }

  // ---- phase 0: per-row meta for all 4 offsets (f32, matches np) ----
  if (t < 64) {
    int q = q0 + t;
    bool valid = q < NQ;
    float c0 = 0.f, c1 = 0.f, e0 = 0.f, e1 = 0.f;
    if (valid) {
      int base = (bb * NQ + q) * 2;
      c0 = coord[base]; c1 = coord[base + 1];
      e0 = cell[base];  e1 = cell[base + 1];
    }
    float rc0 = e0 * 96.0f, rc1 = e1 * 96.0f;
#pragma unroll
    for (int o = 0; o < 4; ++o) {
      float oy = (o < 2) ? -1.0f : 1.0f;     // offsets [-1,-1],[-1,1],[1,-1],[1,1]
      float ox = (o & 1) ? 1.0f : -1.0f;
      float ec0 = (c0 + oy * (1.0f / 96.0f)) + 1e-6f;
      float ec1 = (c1 + ox * (1.0f / 96.0f)) + 1e-6f;
      ec0 = fminf(fmaxf(ec0, -1.0f), 1.0f);  // f32(-1+1e-10) == -1.0f
      ec1 = fminf(fmaxf(ec1, -1.0f), 1.0f);
      int iy = (int)rintf(((ec0 + 1.0f) * 96.0f) * 0.5f - 0.5f);  // half-even
      int ix = (int)rintf(((ec1 + 1.0f) * 96.0f) * 0.5f - 0.5f);
      iy = min(max(iy, 0), 95); ix = min(max(ix, 0), 95);
      float qc0 = -1.0f + (2.0f * (float)iy + 1.0f) / 96.0f;
      float qc1 = -1.0f + (2.0f * (float)ix + 1.0f) / 96.0f;
      float r0 = (c0 - qc0) * 96.0f;
      float r1 = (c1 - qc1) * 96.0f;
      s_pix[o][t]  = (bb * 98 + iy) * 98 + ix;   // padded pixel base
      s_area[o][t] = fabsf(r0 * r1) + 1e-9f;
      s_ext[o][t][0] = to_h(r0);  s_ext[o][t][1] = to_h(r1);
      s_ext[o][t][2] = to_h(rc0); s_ext[o][t][3] = to_h(rc1);
      s_ext[o][t][4] = (_Float16)0.0f; s_ext[o][t][5] = (_Float16)0.0f;
      s_ext[o][t][6] = (_Float16)0.0f; s_ext[o][t][7] = (_Float16)0.0f;
    }
    s_num[t][0] = 0.f; s_num[t][1] = 0.f; s_num[t][2] = 0.f; s_num[t][3] = 0.f;
  }
  __syncthreads();

  const int lane = t & 63;
  const int wv   = t >> 6;
  const int ln32 = lane & 31;
  const int hi   = lane >> 5;
  const int ln16 = lane & 15;
  const int lg   = lane >> 4;

  const _Float16* wb0 = wp0 + (hi * 256 + wv * 64 + ln32) * 8;
  const _Float16* wb1 = wp1 + (hi * 256 + wv * 64 + ln32) * 8;
  const _Float16* wb2 = wp2 + (hi * 256 + wv * 64 + ln32) * 8;
  const _Float16* wb3 = wp3 + (hi * 256 + wv * 64 + ln32) * 8;

#pragma unroll 1
  for (int p = 0; p < 2; ++p) {
    // per-n-tile row meta: row r = nt2*32+ln32, offset = 2p + (r>>6), q = r&63
    int pixr[4]; int eidx[4];
#pragma unroll
    for (int nt2 = 0; nt2 < 4; ++nt2) {
      int r = nt2 * 32 + ln32;
      int o = p * 2 + (r >> 6);
      int q = r & 63;
      pixr[nt2] = s_pix[o][q];
      eidx[nt2] = (o * 64 + q) * 8;              // halves into s_ext
    }

    // ---------------- layer 0: acc init from G + one ext K=16 step --------
    floatx16 acc[2][4];
#pragma unroll
    for (int mt2 = 0; mt2 < 2; ++mt2)
#pragma unroll
      for (int nt2 = 0; nt2 < 4; ++nt2) {
        const _Float16* ga = G + pixr[nt2] * 256 + (wv * 2 + mt2) * 32 + hi * 16;
        half8 g0 = *(const half8*)(ga);
        half8 g1 = *(const half8*)(ga + 8);
        floatx16 a;
#pragma unroll
        for (int j = 0; j < 8; ++j) {
          a[j]     = (float)g0[j];
          a[8 + j] = (float)g1[j];
        }
        acc[mt2][nt2] = a;
      }
    {   // ext step (kb 72+hi): W0 rows 576..591 (rows >= 584 are zero)
      half8 ae[2];
      ae[0] = *(const half8*)(wb0 + 36 * 4096);
      ae[1] = *(const half8*)(wb0 + 36 * 4096 + 256);
      half8 z = {(_Float16)0, (_Float16)0, (_Float16)0, (_Float16)0,
                 (_Float16)0, (_Float16)0, (_Float16)0, (_Float16)0};
      half8 bfe[4];
#pragma unroll
      for (int nt2 = 0; nt2 < 4; ++nt2)
        bfe[nt2] = (hi == 0) ? *(const half8*)(&s_ext[0][0][0] + eidx[nt2]) : z;
#pragma unroll
      for (int mt2 = 0; mt2 < 2; ++mt2)
#pragma unroll
        for (int nt2 = 0; nt2 < 4; ++nt2)
          acc[mt2][nt2] = __builtin_amdgcn_mfma_f32_32x32x16_f16(
              ae[mt2], bfe[nt2], acc[mt2][nt2], 0, 0, 0);
    }
    writeback32(acc, s_bias, s_h, wv, ln32, hi);  // prior L4 reads synced
    __syncthreads();

    // ---------------- layers 1..3: K = 256, ping-pong pipelined -----------
    layer256(wb1, s_h, ln32, hi, acc);
    __syncthreads();                // all reads of s_h done
    writeback32(acc, s_bias + 256, s_h, wv, ln32, hi);
    __syncthreads();

    layer256(wb2, s_h, ln32, hi, acc);
    __syncthreads();
    writeback32(acc, s_bias + 512, s_h, wv, ln32, hi);
    __syncthreads();

    layer256(wb3, s_h, ln32, hi, acc);
    __syncthreads();
    writeback32(acc, s_bias + 768, s_h, wv, ln32, hi);
    __syncthreads();

    // ---------------- layer 4: 256 -> 3 (16x16x32, N padded 16) -----------
    half8 af4 = *(const half8*)(wp4 + (lg * 16 + ln16) * 8);  // s=0
    float4v a4[2];
    a4[0] = (float4v){0.f, 0.f, 0.f, 0.f};
    a4[1] = (float4v){0.f, 0.f, 0.f, 0.f};
#pragma unroll 1
    for (int s = 0; s < 8; ++s) {
      half8 afc = af4;
      if (s < 7)
        af4 = *(const half8*)(wp4 + (((s + 1) * 4 + lg) * 16 + ln16) * 8);
#pragma unroll
      for (int u = 0; u < 2; ++u) {
        int row = (2 * wv + u) * 16 + ln16;
        half8 bf = *(const half8*)(&s_h[row][s * 32 + lg * 8]);
        a4[u] = __builtin_amdgcn_mfma_f32_16x16x32_f16(afc, bf, a4[u], 0, 0, 0);
      }
    }
    if (lg == 0) {                   // lanes 0..15: out-ch j = reg j
#pragma unroll
      for (int u = 0; u < 2; ++u) {
        int row = (2 * wv + u) * 16 + ln16;
        *(float4v*)(&s_out[row][0]) = a4[u];
      }
    }
    __syncthreads();                 // s_out ready; s_h reads done

    if (t < 64) {                    // blend this pass's 2 offsets
      float a_lo = s_area[3 - 2 * p][t];      // rows 0-63:  o = 2p
      float a_hi = s_area[2 - 2 * p][t];      // rows 64-127: o = 2p+1
#pragma unroll
      for (int j = 0; j < 3; ++j)
        s_num[t][j] += s_out[t][j] * a_lo + s_out[64 + t][j] * a_hi;
    }
  }

  // ---- final: out = tanh(num/den + b4) * 1.01, f32 ----
  if (t < 64) {
    int q = q0 + t;
    if (q < NQ) {
      float den = s_area[0][t] + s_area[1][t] + s_area[2][t] + s_area[3][t];
      int ob = (bb * NQ + q) * 3;
#pragma unroll
      for (int j = 0; j < 3; ++j) {
        float v = s_num[t][j] / den + s_bias[1024 + j];
        out[ob + j] = tanhf(v) * 1.01f;
      }
    }
  }
}

// ---------------------------------------------------------------------------
extern "C" void kernel_launch(void* const* d_in, const int* in_sizes, int n_in,
                              void* d_out, int out_size, void* d_ws, size_t ws_size,
                              hipStream_t stream) {
  const float* inp   = (const float*)d_in[0];
  const float* coord = (const float*)d_in[1];
  const float* cell  = (const float*)d_in[2];
  const float* cw    = (const float*)d_in[3];
  const float* cb    = (const float*)d_in[4];
  const float* w0    = (const float*)d_in[5];
  const float* b0    = (const float*)d_in[6];
  const float* w1    = (const float*)d_in[7];
  const float* b1    = (const float*)d_in[8];
  const float* w2    = (const float*)d_in[9];
  const float* b2    = (const float*)d_in[10];
  const float* w3    = (const float*)d_in[11];
  const float* b3    = (const float*)d_in[12];
  const float* w4    = (const float*)d_in[13];
  const float* b4    = (const float*)d_in[14];

  char* ws = (char*)d_ws;
  _Float16* P   = (_Float16*)(ws);            // 2,458,624 B
  _Float16* wp0 = (_Float16*)(ws + 2458624);  //   303,104 B (74 kb)
  _Float16* wp1 = (_Float16*)(ws + 2761728);  //   131,072 B
  _Float16* wp2 = (_Float16*)(ws + 2892800);
  _Float16* wp3 = (_Float16*)(ws + 3023872);
  _Float16* wp4 = (_Float16*)(ws + 3154944);  //     8,192 B
  _Float16* G   = (_Float16*)(ws + 3163136);  // 9,834,496 B (2*98*98*256 f16)
  float* outp = (float*)d_out;

  hipLaunchKernelGGL(prep_kernel, dim3(172), dim3(256), 0, stream,
                     w0, w1, w2, w3, w4, wp0, wp1, wp2, wp3, wp4);
  hipLaunchKernelGGL(conv_kernel, dim3(76), dim3(256), 0, stream, inp, cw, cb, P);
  hipLaunchKernelGGL(gmat_kernel, dim3(144), dim3(256), 0, stream, P, wp0, G);
  hipLaunchKernelGGL(liif_main, dim3(8 * (QTP / 4)), dim3(256), 0, stream,
                     coord, cell, b0, b1, b2, b3, b4,
                     G, wp0, wp1, wp2, wp3, wp4, outp);
}

// Round 16
// 264.352 us; speedup vs baseline: 1.0350x; 1.0350x over previous
//
#include <hip/hip_runtime.h>

// ---------------------------------------------------------------------------
// LIIF forward, MI355X.  ALL tensors are float32 (per reference source).
// R16 = R14/R15 with ONE change: gmat_kernel rewritten with LDS-staged P.
//   R15 post-mortem: gmat ~45 us is TRANSACTION-bound, not latency-bound
//   (16B/lane loads at 128B stride = ~64 lines per load instr; prefetch
//   depth 1->3 changed nothing).  New gmat: 1 WG = 1 window-base row
//   (192 WGs = 2 batches x 96 rows, batch = bit2 of blockIdx -> same XCD
//   rule as liif so liif's G reads hit the producing XCD's L2).  P rows
//   y..y+2 staged to LDS coalesced, pixel stride padded to 68 halves
//   (34 dw = 2 mod 32 -> 2-way bank conflict = free, m136).  B-frags from
//   LDS; weights ping-pong (constant indices).  acc 2m x 3n = 96 AGPR at
//   launch_bounds(256,1): no spill.  Same math, same G layout.
// R12 recap: G[pixel] = W0[0:576]^T unfold(pixel) in MFMA C-layout order
// (ch' = mt*32+hi*16+q*4+i <-> m = 8q+4hi+i); liif L0 = G gather (acc init)
// + one K=16 ext MFMA step; layers 1-3 32x32x16 ping-pong, packed cvt
// writeback, post-barrier weight loads.  liif = 121 us @ MfmaUtil 35%.
// Tripwires: liif counters unchanged (byte-identical); absmax > 5.86e-3 =>
// bug; total improvement < 15 us => gap is harness-fixed floor -> declare.
// ---------------------------------------------------------------------------

typedef _Float16 half8   __attribute__((ext_vector_type(8)));
typedef _Float16 half4v  __attribute__((ext_vector_type(4)));
typedef _Float16 half2v  __attribute__((ext_vector_type(2)));
typedef float    float4v __attribute__((ext_vector_type(4)));
typedef float    floatx16 __attribute__((ext_vector_type(16)));

// clamped f32->f16 (prep/conv side only)
__device__ __forceinline__ _Float16 to_h(float v) {
  return (_Float16)fminf(fmaxf(v, -60000.0f), 60000.0f);
}

#define NQ 30000
#define QT 469   // ceil(NQ/64) real tiles per batch
#define QTP 472  // padded to 4-multiple for XCD-partitioned grid (944 blocks)

// ---------------- weight repack (coalesced, R14) ---------------------------
// wp layout: [kb][n][8] f16, element (n, k=kb*8+i) at ((kb*N + n)*8 + i).
__global__ void prep_kernel(const float* __restrict__ w0,
                            const float* __restrict__ w1,
                            const float* __restrict__ w2,
                            const float* __restrict__ w3,
                            const float* __restrict__ w4,
                            _Float16* __restrict__ p0, _Float16* __restrict__ p1,
                            _Float16* __restrict__ p2, _Float16* __restrict__ p3,
                            _Float16* __restrict__ p4) {
  int idx = blockIdx.x * 256 + threadIdx.x;
  if (idx < 18944) {                       // wp0: (kb,n), kb 0..73
    int kb = idx >> 8, n = idx & 255;
    half8 hv;
#pragma unroll
    for (int i = 0; i < 8; ++i) {
      int f = kb * 8 + i;                  // permuted feature index
      float v = 0.0f;
      if (f < 576)      v = w0[((f & 63) * 9 + (f >> 6)) * 256 + n];
      else if (f < 580) v = w0[f * 256 + n];
      hv[i] = (_Float16)v;
    }
    *(half8*)(p0 + idx * 8) = hv;
  } else if (idx < 43520) {                // wp1..3: l*(32kb*256n)
    int j = idx - 18944;
    int l = j >> 13;                       // 8192 = 32*256 per layer
    int j2 = j & 8191;
    int kb = j2 >> 8, n = j2 & 255;
    const float* w = (l == 0) ? w1 : (l == 1) ? w2 : w3;
    _Float16* p = (l == 0) ? p1 : (l == 1) ? p2 : p3;
    half8 hv;
#pragma unroll
    for (int i = 0; i < 8; ++i)
      hv[i] = (_Float16)w[(kb * 8 + i) * 256 + n];
    *(half8*)(p + j2 * 8) = hv;
  } else if (idx < 44032) {                // wp4: 32kb * 16n
    int j = idx - 43520;
    int kb = j >> 4, n = j & 15;
    half8 hv;
#pragma unroll
    for (int i = 0; i < 8; ++i) {
      float v = (n < 3) ? w4[(kb * 8 + i) * 3 + n] : 0.0f;
      hv[i] = (_Float16)v;
    }
    *(half8*)(p4 + j * 8) = hv;
  }
}

// ---------------- conv 3x3 (3->64) + bias + tanh, zero-padded borders ------
__global__ void conv_kernel(const float* __restrict__ inp,
                            const float* __restrict__ cw,
                            const float* __restrict__ cb,
                            _Float16* __restrict__ P) {
  __shared__ __align__(16) float s_w[1728];
  __shared__ __align__(16) float s_b[64];
  for (int i = threadIdx.x; i < 1728; i += 256) s_w[i] = cw[i];
  if (threadIdx.x < 64) s_b[threadIdx.x] = cb[threadIdx.x];
  __syncthreads();
  int tid = blockIdx.x * 256 + threadIdx.x;
  if (tid >= 2 * 98 * 98) return;
  int b = tid / 9604;
  int rem = tid % 9604;
  int yy = rem / 98, xx = rem % 98;
  alignas(16) _Float16 outv[64];
  if (yy == 0 || yy == 97 || xx == 0 || xx == 97) {
#pragma unroll
    for (int c = 0; c < 64; ++c) outv[c] = (_Float16)0.0f;
  } else {
    int y = yy - 1, x = xx - 1;
    float win[27];
#pragma unroll
    for (int ci = 0; ci < 3; ++ci)
#pragma unroll
      for (int ky = 0; ky < 3; ++ky)
#pragma unroll
        for (int kx = 0; kx < 3; ++kx) {
          int yi = y + ky - 1, xi = x + kx - 1;
          float v = 0.0f;
          if (yi >= 0 && yi < 96 && xi >= 0 && xi < 96)
            v = inp[((b * 3 + ci) * 96 + yi) * 96 + xi];
          win[ci * 9 + ky * 3 + kx] = v;
        }
    for (int co = 0; co < 64; ++co) {
      float acc = s_b[co];
#pragma unroll
      for (int k = 0; k < 27; ++k) acc = fmaf(win[k], s_w[co * 27 + k], acc);
      outv[co] = (_Float16)tanhf(acc);
    }
  }
  _Float16* dst = P + tid * 64;
#pragma unroll
  for (int j = 0; j < 8; ++j) ((half8*)dst)[j] = ((const half8*)outv)[j];
}

// ---------------- G precompute (R16: LDS-staged) ---------------------------
// G[pix] = W0[0:576]^T * unfold(pix).  1 WG = 1 window-base row: 96 pixels.
// Grid 192: bb = bit2(blk) (same XCD rule as liif), y = (blk>>3)*4+(blk&3).
// LDS s_p[3][98][68]: P rows y..y+2 staged coalesced; pixel stride 68
// halves = 34 dw = 2 mod 32 -> <=2-way bank conflicts (free).
// acc 2 m-tile-pairs x 3 n-tiles; store pre-permuted (same layout as R12):
// value m = 8q+4hi+i of tile mt at G[pix*256 + mt*32 + hi*16 + q*4 + i].
__global__ __launch_bounds__(256, 1) void gmat_kernel(
    const _Float16* __restrict__ P,
    const _Float16* __restrict__ wp0,
    _Float16* __restrict__ G) {
  __shared__ __align__(16) _Float16 s_p[3][98][68];

  const int t    = threadIdx.x;
  const int lane = t & 63;
  const int wv   = t >> 6;
  const int ln32 = lane & 31;
  const int hi   = lane >> 5;
  const int blk  = blockIdx.x;
  const int bb   = (blk & 4) >> 2;               // batch, matches liif XCD rule
  const int y    = (blk >> 3) * 4 + (blk & 3);   // window-base row 0..95

  // ---- stage P rows y..y+2 (3 x 98 pixels x 64 ch) coalesced ----
  const int rowbase = (bb * 98 + y) * 98 * 64;   // element idx of row y
  for (int j = t; j < 2352; j += 256) {          // 2352 = 3*98*8 chunks
    int row = j / 784;                           // 784 = 98*8
    int jr  = j - row * 784;
    int px  = jr >> 3;
    int ci  = jr & 7;
    half8 v = *(const half8*)(P + rowbase + row * 6272 + jr * 8);
    *(half8*)(&s_p[row][px][ci * 8]) = v;
  }
  __syncthreads();

  const _Float16* wb0 = wp0 + (hi * 256 + wv * 64 + ln32) * 8;

  floatx16 acc[2][3];
#pragma unroll
  for (int mt2 = 0; mt2 < 2; ++mt2)
#pragma unroll
    for (int nt = 0; nt < 3; ++nt) acc[mt2][nt] = (floatx16)(0.0f);

  half8 afA[2], afB[2];
  afA[0] = *(const half8*)(wb0);          afA[1] = *(const half8*)(wb0 + 256);
  afB[0] = *(const half8*)(wb0 + 4096);   afB[1] = *(const half8*)(wb0 + 4096 + 256);

#pragma unroll 1
  for (int s = 0; s < 36; s += 2) {
    // step s (A)
    {
      const int patch = s >> 2;
      const int py = patch / 3, px = patch % 3;
      const int cb = ((s & 3) << 4) + hi * 8;
      half8 bf[3];
#pragma unroll
      for (int nt = 0; nt < 3; ++nt)
        bf[nt] = *(const half8*)(&s_p[py][nt * 32 + ln32 + px][cb]);
#pragma unroll
      for (int mt2 = 0; mt2 < 2; ++mt2)
#pragma unroll
        for (int nt = 0; nt < 3; ++nt)
          acc[mt2][nt] = __builtin_amdgcn_mfma_f32_32x32x16_f16(
              afA[mt2], bf[nt], acc[mt2][nt], 0, 0, 0);
      const int sp = (s + 2 <= 35) ? (s + 2) : 35;   // weight prefetch
      afA[0] = *(const half8*)(wb0 + sp * 4096);
      afA[1] = *(const half8*)(wb0 + sp * 4096 + 256);
    }
    // step s+1 (B)
    {
      const int s1 = s + 1;
      const int patch = s1 >> 2;
      const int py = patch / 3, px = patch % 3;
      const int cb = ((s1 & 3) << 4) + hi * 8;
      half8 bf[3];
#pragma unroll
      for (int nt = 0; nt < 3; ++nt)
        bf[nt] = *(const half8*)(&s_p[py][nt * 32 + ln32 + px][cb]);
#pragma unroll
      for (int mt2 = 0; mt2 < 2; ++mt2)
#pragma unroll
        for (int nt = 0; nt < 3; ++nt)
          acc[mt2][nt] = __builtin_amdgcn_mfma_f32_32x32x16_f16(
              afB[mt2], bf[nt], acc[mt2][nt], 0, 0, 0);
      const int sp = (s + 3 <= 35) ? (s + 3) : 35;
      afB[0] = *(const half8*)(wb0 + sp * 4096);
      afB[1] = *(const half8*)(wb0 + sp * 4096 + 256);
    }
  }
  // permuted store (RNE cvt): regs 0..15 already in ch' order q*4+i
  const int gybase = ((bb * 98 + y) * 98) * 256;
#pragma unroll
  for (int mt2 = 0; mt2 < 2; ++mt2)
#pragma unroll
    for (int nt = 0; nt < 3; ++nt) {
      half8 c0, c1;
#pragma unroll
      for (int j = 0; j < 8; ++j) {
        c0[j] = (_Float16)acc[mt2][nt][j];
        c1[j] = (_Float16)acc[mt2][nt][8 + j];
      }
      _Float16* ga = G + gybase + (nt * 32 + ln32) * 256 + (wv * 2 + mt2) * 32 + hi * 16;
      *(half8*)(ga)     = c0;
      *(half8*)(ga + 8) = c1;
    }
}

// ---------------- main: gather + MLP + blend -------------------------------
// WG = 256 thr = 4 waves = 64 queries x 2 offsets (128 rows) per pass.
// 32x32x16 C/D (measured m74/m101): n=lane&31, m=(reg&3)+8*(reg>>2)+4*(lane>>5).
__device__ __forceinline__ void writeback32(floatx16 (&acc)[2][4],
                                            const float* __restrict__ sb,
                                            _Float16 (*s_h)[264],
                                            int wv, int ln32, int hi) {
#pragma unroll
  for (int mt2 = 0; mt2 < 2; ++mt2) {
    const int mb = wv * 64 + mt2 * 32 + 4 * hi;
#pragma unroll
    for (int g = 0; g < 4; ++g) {
      const int m0 = mb + 8 * g;
      float b0 = sb[m0], b1 = sb[m0 + 1], b2 = sb[m0 + 2], b3 = sb[m0 + 3];
#pragma unroll
      for (int nt2 = 0; nt2 < 4; ++nt2) {
        const int n = nt2 * 32 + ln32;
        float v0 = fmaxf(acc[mt2][nt2][4 * g + 0] + b0, 0.0f);
        float v1 = fmaxf(acc[mt2][nt2][4 * g + 1] + b1, 0.0f);
        float v2 = fmaxf(acc[mt2][nt2][4 * g + 2] + b2, 0.0f);
        float v3 = fmaxf(acc[mt2][nt2][4 * g + 3] + b3, 0.0f);
        half2v lo  = __builtin_bit_cast(half2v, __builtin_amdgcn_cvt_pkrtz(v0, v1));
        half2v hi2 = __builtin_bit_cast(half2v, __builtin_amdgcn_cvt_pkrtz(v2, v3));
        half4v hv;
        hv[0] = lo[0]; hv[1] = lo[1]; hv[2] = hi2[0]; hv[3] = hi2[1];
        *(half4v*)(&s_h[n][m0]) = hv;
      }
    }
  }
}

// K=256 layer from s_h, ping-pong pipelined; loads after caller's barrier.
__device__ __forceinline__ void layer256(const _Float16* __restrict__ wbl,
                                         _Float16 (*s_h)[264],
                                         int ln32, int hi,
                                         floatx16 (&acc)[2][4]) {
#pragma unroll
  for (int mt2 = 0; mt2 < 2; ++mt2)
#pragma unroll
    for (int nt2 = 0; nt2 < 4; ++nt2) acc[mt2][nt2] = (floatx16)(0.0f);
  half8 afA[2], afB[2], bfA[4], bfB[4];
  afA[0] = *(const half8*)(wbl);
  afA[1] = *(const half8*)(wbl + 256);
  afB[0] = *(const half8*)(wbl + 4096);
  afB[1] = *(const half8*)(wbl + 4096 + 256);
#pragma unroll
  for (int nt2 = 0; nt2 < 4; ++nt2) {
    bfA[nt2] = *(const half8*)(&s_h[nt2 * 32 + ln32][hi * 8]);
    bfB[nt2] = *(const half8*)(&s_h[nt2 * 32 + ln32][16 + hi * 8]);
  }
#pragma unroll 1
  for (int s = 0; s < 16; s += 2) {
#pragma unroll
    for (int mt2 = 0; mt2 < 2; ++mt2)
#pragma unroll
      for (int nt2 = 0; nt2 < 4; ++nt2)
        acc[mt2][nt2] = __builtin_amdgcn_mfma_f32_32x32x16_f16(
            afA[mt2], bfA[nt2], acc[mt2][nt2], 0, 0, 0);
    {
      const int sc = (s + 2 < 16) ? (s + 2) : 0;
      const int sw = (s + 2 < 16) ? (s + 2) : 15;
      afA[0] = *(const half8*)(wbl + sw * 4096);
      afA[1] = *(const half8*)(wbl + sw * 4096 + 256);
#pragma unroll
      for (int nt2 = 0; nt2 < 4; ++nt2)
        bfA[nt2] = *(const half8*)(&s_h[nt2 * 32 + ln32][sc * 16 + hi * 8]);
    }
#pragma unroll
    for (int mt2 = 0; mt2 < 2; ++mt2)
#pragma unroll
      for (int nt2 = 0; nt2 < 4; ++nt2)
        acc[mt2][nt2] = __builtin_amdgcn_mfma_f32_32x32x16_f16(
            afB[mt2], bfB[nt2], acc[mt2][nt2], 0, 0, 0);
    {
      const int sc = (s + 3 < 16) ? (s + 3) : 0;
      const int sw = (s + 3 < 16) ? (s + 3) : 15;
      afB[0] = *(const half8*)(wbl + sw * 4096);
      afB[1] = *(const half8*)(wbl + sw * 4096 + 256);
#pragma unroll
      for (int nt2 = 0; nt2 < 4; ++nt2)
        bfB[nt2] = *(const half8*)(&s_h[nt2 * 32 + ln32][sc * 16 + hi * 8]);
    }
  }
}

__global__ __launch_bounds__(256, 2) void liif_main(
    const float* __restrict__ coord, const float* __restrict__ cell,
    const float* __restrict__ bias0, const float* __restrict__ bias1,
    const float* __restrict__ bias2, const float* __restrict__ bias3,
    const float* __restrict__ bias4,
    const _Float16* __restrict__ G,
    const _Float16* __restrict__ wp0, const _Float16* __restrict__ wp1,
    const _Float16* __restrict__ wp2, const _Float16* __restrict__ wp3,
    const _Float16* __restrict__ wp4,
    float* __restrict__ out) {
  __shared__ __align__(16) int      s_pix[4][64];
  __shared__ __align__(16) float    s_area[4][64];
  __shared__ __align__(16) _Float16 s_ext[4][64][8];
  __shared__ __align__(16) float    s_bias[1028];
  __shared__ __align__(16) float    s_out[128][4];
  __shared__ __align__(16) float    s_num[64][4];
  __shared__ __align__(16) _Float16 s_h[128][264]; // stride 132 dw = 4 mod 32

  const int t   = threadIdx.x;
  const int blk = blockIdx.x;
  const int bb  = (blk & 4) >> 2;            // batch = bit2 -> stable per XCD
  const int tile = (blk >> 3) * 4 + (blk & 3);
  const int q0  = tile * 64;

  // ---- stage biases into LDS (1027 f32) ----
  for (int i = t; i < 1027; i += 256) {
    float v;
    if (i < 256)       v = bias0[i];
    else if (i < 512)  v = bias1[i - 256];
    else if (i < 768)  v = bias2[i - 512];
    else if (i < 1024) v = bias3[i - 768];
    else               v = bias4[i - 1024];
    s_bias[i] = v;
  }

  // ---- phase 0: per-row meta for all 4 offsets (f32, matches np) ----
  if (t < 64) {
    int q = q0 + t;
    bool valid = q < NQ;
    float c0 = 0.f, c1 = 0.f, e0 = 0.f, e1 = 0.f;
    if (valid) {
      int base = (bb * NQ + q) * 2;
      c0 = coord[base]; c1 = coord[base + 1];
      e0 = cell[base];  e1 = cell[base + 1];
    }
    float rc0 = e0 * 96.0f, rc1 = e1 * 96.0f;
#pragma unroll
    for (int o = 0; o < 4; ++o) {
      float oy = (o < 2) ? -1.0f : 1.0f;     // offsets [-1,-1],[-1,1],[1,-1],[1,1]
      float ox = (o & 1) ? 1.0f : -1.0f;
      float ec0 = (c0 + oy * (1.0f / 96.0f)) + 1e-6f;
      float ec1 = (c1 + ox * (1.0f / 96.0f)) + 1e-6f;
      ec0 = fminf(fmaxf(ec0, -1.0f), 1.0f);  // f32(-1+1e-10) == -1.0f
      ec1 = fminf(fmaxf(ec1, -1.0f), 1.0f);
      int iy = (int)rintf(((ec0 + 1.0f) * 96.0f) * 0.5f - 0.5f);  // half-even
      int ix = (int)rintf(((ec1 + 1.0f) * 96.0f) * 0.5f - 0.5f);
      iy = min(max(iy, 0), 95); ix = min(max(ix, 0), 95);
      float qc0 = -1.0f + (2.0f * (float)iy + 1.0f) / 96.0f;
      float qc1 = -1.0f + (2.0f * (float)ix + 1.0f) / 96.0f;
      float r0 = (c0 - qc0) * 96.0f;
      float r1 = (c1 - qc1) * 96.0f;
      s_pix[o][t]  = (bb * 98 + iy) * 98 + ix;   // padded pixel base
      s_area[o][t] = fabsf(r0 * r1) + 1e-9f;
      s_ext[o][t][0] = to_h(r0);  s_ext[o][t][1] = to_h(r1);
      s_ext[o][t][2] = to_h(rc0); s_ext[o][t][3] = to_h(rc1);
      s_ext[o][t][4] = (_Float16)0.0f; s_ext[o][t][5] = (_Float16)0.0f;
      s_ext[o][t][6] = (_Float16)0.0f; s_ext[o][t][7] = (_Float16)0.0f;
    }
    s_num[t][0] = 0.f; s_num[t][1] = 0.f; s_num[t][2] = 0.f; s_num[t][3] = 0.f;
  }
  __syncthreads();

  const int lane = t & 63;
  const int wv   = t >> 6;
  const int ln32 = lane & 31;
  const int hi   = lane >> 5;
  const int ln16 = lane & 15;
  const int lg   = lane >> 4;

  const _Float16* wb0 = wp0 + (hi * 256 + wv * 64 + ln32) * 8;
  const _Float16* wb1 = wp1 + (hi * 256 + wv * 64 + ln32) * 8;
  const _Float16* wb2 = wp2 + (hi * 256 + wv * 64 + ln32) * 8;
  const _Float16* wb3 = wp3 + (hi * 256 + wv * 64 + ln32) * 8;

#pragma unroll 1
  for (int p = 0; p < 2; ++p) {
    // per-n-tile row meta: row r = nt2*32+ln32, offset = 2p + (r>>6), q = r&63
    int pixr[4]; int eidx[4];
#pragma unroll
    for (int nt2 = 0; nt2 < 4; ++nt2) {
      int r = nt2 * 32 + ln32;
      int o = p * 2 + (r >> 6);
      int q = r & 63;
      pixr[nt2] = s_pix[o][q];
      eidx[nt2] = (o * 64 + q) * 8;              // halves into s_ext
    }

    // ---------------- layer 0: acc init from G + one ext K=16 step --------
    floatx16 acc[2][4];
#pragma unroll
    for (int mt2 = 0; mt2 < 2; ++mt2)
#pragma unroll
      for (int nt2 = 0; nt2 < 4; ++nt2) {
        const _Float16* ga = G + pixr[nt2] * 256 + (wv * 2 + mt2) * 32 + hi * 16;
        half8 g0 = *(const half8*)(ga);
        half8 g1 = *(const half8*)(ga + 8);
        floatx16 a;
#pragma unroll
        for (int j = 0; j < 8; ++j) {
          a[j]     = (float)g0[j];
          a[8 + j] = (float)g1[j];
        }
        acc[mt2][nt2] = a;
      }
    {   // ext step (kb 72+hi): W0 rows 576..591 (rows >= 584 are zero)
      half8 ae[2];
      ae[0] = *(const half8*)(wb0 + 36 * 4096);
      ae[1] = *(const half8*)(wb0 + 36 * 4096 + 256);
      half8 z = {(_Float16)0, (_Float16)0, (_Float16)0, (_Float16)0,
                 (_Float16)0, (_Float16)0, (_Float16)0, (_Float16)0};
      half8 bfe[4];
#pragma unroll
      for (int nt2 = 0; nt2 < 4; ++nt2)
        bfe[nt2] = (hi == 0) ? *(const half8*)(&s_ext[0][0][0] + eidx[nt2]) : z;
#pragma unroll
      for (int mt2 = 0; mt2 < 2; ++mt2)
#pragma unroll
        for (int nt2 = 0; nt2 < 4; ++nt2)
          acc[mt2][nt2] = __builtin_amdgcn_mfma_f32_32x32x16_f16(
              ae[mt2], bfe[nt2], acc[mt2][nt2], 0, 0, 0);
    }
    writeback32(acc, s_bias, s_h, wv, ln32, hi);  // prior L4 reads synced
    __syncthreads();

    // ---------------- layers 1..3: K = 256, ping-pong pipelined -----------
    layer256(wb1, s_h, ln32, hi, acc);
    __syncthreads();                // all reads of s_h done
    writeback32(acc, s_bias + 256, s_h, wv, ln32, hi);
    __syncthreads();

    layer256(wb2, s_h, ln32, hi, acc);
    __syncthreads();
    writeback32(acc, s_bias + 512, s_h, wv, ln32, hi);
    __syncthreads();

    layer256(wb3, s_h, ln32, hi, acc);
    __syncthreads();
    writeback32(acc, s_bias + 768, s_h, wv, ln32, hi);
    __syncthreads();

    // ---------------- layer 4: 256 -> 3 (16x16x32, N padded 16) -----------
    half8 af4 = *(const half8*)(wp4 + (lg * 16 + ln16) * 8);  // s=0
    float4v a4[2];
    a4[0] = (float4v){0.f, 0.f, 0.f, 0.f};
    a4[1] = (float4v){0.f, 0.f, 0.f, 0.f};
#pragma unroll 1
    for (int s = 0; s < 8; ++s) {
      half8 afc = af4;
      if (s < 7)
        af4 = *(const half8*)(wp4 + (((s + 1) * 4 + lg) * 16 + ln16) * 8);
#pragma unroll
      for (int u = 0; u < 2; ++u) {
        int row = (2 * wv + u) * 16 + ln16;
        half8 bf = *(const half8*)(&s_h[row][s * 32 + lg * 8]);
        a4[u] = __builtin_amdgcn_mfma_f32_16x16x32_f16(afc, bf, a4[u], 0, 0, 0);
      }
    }
    if (lg == 0) {                   // lanes 0..15: out-ch j = reg j
#pragma unroll
      for (int u = 0; u < 2; ++u) {
        int row = (2 * wv + u) * 16 + ln16;
        *(float4v*)(&s_out[row][0]) = a4[u];
      }
    }
    __syncthreads();                 // s_out ready; s_h reads done

    if (t < 64) {                    // blend this pass's 2 offsets
      float a_lo = s_area[3 - 2 * p][t];      // rows 0-63:  o = 2p
      float a_hi = s_area[2 - 2 * p][t];      // rows 64-127: o = 2p+1
#pragma unroll
      for (int j = 0; j < 3; ++j)
        s_num[t][j] += s_out[t][j] * a_lo + s_out[64 + t][j] * a_hi;
    }
  }

  // ---- final: out = tanh(num/den + b4) * 1.01, f32 ----
  if (t < 64) {
    int q = q0 + t;
    if (q < NQ) {
      float den = s_area[0][t] + s_area[1][t] + s_area[2][t] + s_area[3][t];
      int ob = (bb * NQ + q) * 3;
#pragma unroll
      for (int j = 0; j < 3; ++j) {
        float v = s_num[t][j] / den + s_bias[1024 + j];
        out[ob + j] = tanhf(v) * 1.01f;
      }
    }
  }
}

// ---------------------------------------------------------------------------
extern "C" void kernel_launch(void* const* d_in, const int* in_sizes, int n_in,
                              void* d_out, int out_size, void* d_ws, size_t ws_size,
                              hipStream_t stream) {
  const float* inp   = (const float*)d_in[0];
  const float* coord = (const float*)d_in[1];
  const float* cell  = (const float*)d_in[2];
  const float* cw    = (const float*)d_in[3];
  const float* cb    = (const float*)d_in[4];
  const float* w0    = (const float*)d_in[5];
  const float* b0    = (const float*)d_in[6];
  const float* w1    = (const float*)d_in[7];
  const float* b1    = (const float*)d_in[8];
  const float* w2    = (const float*)d_in[9];
  const float* b2    = (const float*)d_in[10];
  const float* w3    = (const float*)d_in[11];
  const float* b3    = (const float*)d_in[12];
  const float* w4    = (const float*)d_in[13];
  const float* b4    = (const float*)d_in[14];

  char* ws = (char*)d_ws;
  _Float16* P   = (_Float16*)(ws);            // 2,458,624 B
  _Float16* wp0 = (_Float16*)(ws + 2458624);  //   303,104 B (74 kb)
  _Float16* wp1 = (_Float16*)(ws + 2761728);  //   131,072 B
  _Float16* wp2 = (_Float16*)(ws + 2892800);
  _Float16* wp3 = (_Float16*)(ws + 3023872);
  _Float16* wp4 = (_Float16*)(ws + 3154944);  //     8,192 B
  _Float16* G   = (_Float16*)(ws + 3163136);  // 9,834,496 B (2*98*98*256 f16)
  float* outp = (float*)d_out;

  hipLaunchKernelGGL(prep_kernel, dim3(172), dim3(256), 0, stream,
                     w0, w1, w2, w3, w4, wp0, wp1, wp2, wp3, wp4);
  hipLaunchKernelGGL(conv_kernel, dim3(76), dim3(256), 0, stream, inp, cw, cb, P);
  hipLaunchKernelGGL(gmat_kernel, dim3(192), dim3(256), 0, stream, P, wp0, G);
  hipLaunchKernelGGL(liif_main, dim3(8 * (QTP / 4)), dim3(256), 0, stream,
                     coord, cell, b0, b1, b2, b3, b4,
                     G, wp0, wp1, wp2, wp3, wp4, outp);
}